// Round 7
// baseline (552.323 us; speedup 1.0000x reference)
//
#include <hip/hip_runtime.h>

// ---------------------------------------------------------------------------
// YOLO NMS post-processing for MI355X — 6-launch pipeline.
//   zero -> score (+16-way sliced hist) -> reduce+select (last-block
//   handshake) -> compact -> rank+scatter -> nms_fused (IoU + greedy scan +
//   output, all in LDS -- NO global IoU mask).
//
// Round-6 lesson: any scan that round-trips the mask through global memory is
// latency-bound 40-225 us (single consumer wave vs remote-XCD-produced data;
// compiler emits conservative vmcnt(0) under divergent control flow). Fix:
// never materialize the mask. nms_fused (1 block, 512 thr):
//   * 4096 sorted boxes -> LDS (64 KB) + areas (16 KB), loaded once.
//   * all 64 diagonal 64x64 IoU blocks -> LDS (32 KB): in-batch decision
//     matrices, ~260k IoUs across 8 waves (~4 us).
//   * per live batch w: wave 0 runs the serial decision chain on the diag
//     block (ctz -> readlane64 -> andn2, ~30 cy/keep; remv[w] ends as
//     ~keptM); then ALL 512 threads suppress this batch's keeps against
//     their own 8 REGISTER-cached future slots, skipping already-dead slots
//     (alive set decays geometrically per keep -> total IoUs ~ 4096/p) and
//     atomicOr new kills into LDS remv. Two __syncthreads per live batch;
//     dead batches (cand==0, uniform) skip with no barrier.
//   * fillers (score -1) = set bits of remv ascending (remv[w] = ~keptM
//     exactly: every non-kept slot of a processed batch is marked).
//   * output (boxes/cls/score/masks) written by all threads at the end.
// All IoU-relevant fp32 math uses _rn intrinsics so hipcc's default
// -ffp-contract=fast cannot fuse mul+add into fma (must match numpy fp32).
// ---------------------------------------------------------------------------

typedef unsigned long long u64;

constexpr int N_ANCH = 100800;
constexpr int DIMV   = 117;   // 4 box + 1 obj + 80 cls + 32 mask
constexpr int TOPKN  = 4096;
constexpr int MAXDET = 300;
constexpr int KCAP   = 12288; // candidate capacity
constexpr int NBUCK  = 16384; // scores < 1.0 -> bits>>16 < 0x3F80 < 16384
constexpr int NSLICE = 16;

// workspace layout (bytes)
constexpr size_t WS_HIST   = 0;                                   // 16384 u32
constexpr size_t WS_SEL    = WS_HIST   + 65536;                   // 64 i32
constexpr size_t WS_DONE   = WS_SEL    + 256;                     // 1 u32 (+pad)
constexpr size_t WS_SLICES = WS_DONE   + 256;                     // 16*16384 u32
constexpr size_t WS_SCORES = WS_SLICES + (size_t)NSLICE * NBUCK * 4;
constexpr size_t WS_CLS    = WS_SCORES + (size_t)N_ANCH * 4;
constexpr size_t WS_KEYS   = WS_CLS    + (size_t)N_ANCH * 4;      // 12288 u64
constexpr size_t WS_SIDX   = WS_KEYS   + (size_t)KCAP * 8;        // 4096 i32
constexpr size_t WS_SSC    = WS_SIDX   + 4096ull * 4;             // 4096 f32
constexpr size_t WS_BOXES  = WS_SSC    + 4096ull * 4;             // 4096*4 f32

__global__ void zero_kernel(unsigned* __restrict__ slices, int* __restrict__ sel,
                            unsigned* __restrict__ done) {
    int i = blockIdx.x * 256 + threadIdx.x;
    if (i < NSLICE * NBUCK) slices[i] = 0u;
    if (i < 64)             sel[i]    = 0;
    if (i == 0)             *done     = 0u;
}

// 64 rows per 128-thread block, staged to LDS with coalesced float4 loads.
// 2 threads per row: even lane scans classes 0..39, odd lane 40..79, merged
// via shfl_xor. Strict > keeps the first (lowest-class) argmax like numpy.
constexpr int SROWS = 64;
__global__ void score_kernel(const float* __restrict__ x, float* __restrict__ scores,
                             int* __restrict__ cls, unsigned* __restrict__ slices) {
    __shared__ float sx[SROWS * DIMV];           // 29952 B
    int block0 = blockIdx.x * SROWS;
    const float4* src = (const float4*)(x + (size_t)block0 * DIMV); // 64*468 % 16 == 0
    float4* dst = (float4*)sx;
    constexpr int NV4 = SROWS * DIMV / 4;        // 1872
    for (int i = threadIdx.x; i < NV4; i += 128) dst[i] = src[i];
    __syncthreads();
    int row  = threadIdx.x >> 1;
    int half = threadIdx.x & 1;
    const float* rp = sx + row * DIMV;
    float obj = rp[4];
    const float* cp = rp + 5 + half * 40;
    float best = -1.0f;
    int   bc   = half * 40;
#pragma unroll 8
    for (int c = 0; c < 40; ++c) {
        float s = __fmul_rn(cp[c], obj);
        if (s > best) { best = s; bc = half * 40 + c; }
    }
    float so = __shfl_xor(best, 1);
    int   co = __shfl_xor(bc, 1);
    if (half == 0) {
        if (so > best) { best = so; bc = co; }   // strict >: even (lower classes) wins ties
        int a = block0 + row;
        bool valid = obj > 0.25f;
        scores[a] = valid ? best : -1.0f;
        cls[a]    = bc;
        if (valid) {
            unsigned b = __float_as_uint(best) >> 16;   // < 16384 (best in [0,1))
            atomicAdd(&slices[(blockIdx.x & (NSLICE - 1)) * NBUCK + b], 1u);
        }
    }
}

// fold 16 slices -> hist (64 blocks x 256), then the LAST block (device-scope
// ticket; rounds 5/6 evidence: threadfence release/acquire + agent atomics
// are cross-XCD safe) runs select: bucket B with
// cntAbove(B) < 4096 <= cntAbove(B)+hist[B]. Thread t owns 64 buckets.
__global__ void reduce_select_kernel(const unsigned* __restrict__ slices,
                                     unsigned* __restrict__ hist,
                                     int* __restrict__ sel,
                                     unsigned* __restrict__ done) {
    int b = blockIdx.x * 256 + threadIdx.x;
    unsigned s = 0;
#pragma unroll
    for (int k = 0; k < NSLICE; ++k) s += slices[(size_t)k * NBUCK + b];
    hist[b] = s;
    __threadfence();                      // release hist writes
    __syncthreads();
    __shared__ unsigned tick;
    if (threadIdx.x == 0)
        tick = __hip_atomic_fetch_add(done, 1u, __ATOMIC_ACQ_REL,
                                      __HIP_MEMORY_SCOPE_AGENT);
    __syncthreads();
    if (tick != 63) return;               // not the last block
    __threadfence();                      // acquire: fresh hist reads

    __shared__ unsigned sv[256];
    __shared__ int bsh[2];
    int t = threadIdx.x;
    int base = NBUCK - 64 * (t + 1);      // chunk t = 64 buckets, t=0 = top
    const uint4* hp = (const uint4*)(hist + base);
    unsigned own = 0;
#pragma unroll
    for (int q = 0; q < 16; ++q) { uint4 v = hp[q]; own += v.x + v.y + v.z + v.w; }
    sv[t] = own;
    __syncthreads();
    for (int off = 1; off < 256; off <<= 1) {     // inclusive scan (desc-chunk order)
        unsigned v = (t >= off) ? sv[t - off] : 0u;
        __syncthreads();
        sv[t] += v;
        __syncthreads();
    }
    unsigned incl = sv[t], before = incl - own;
    if (before < (unsigned)TOPKN && incl >= (unsigned)TOPKN) {
        bsh[0] = t; bsh[1] = (int)before;
    }
    __syncthreads();
    if (t == 0) {
        int ts = bsh[0];
        unsigned running = (unsigned)bsh[1];
        int cbase = NBUCK - 64 * (ts + 1);
        unsigned hh[64];
#pragma unroll
        for (int u = 0; u < 64; ++u) hh[u] = hist[cbase + 63 - u];  // independent loads
        for (int u = 0; u < 64; ++u) {
            if (running + hh[u] >= (unsigned)TOPKN) { sel[0] = cbase + 63 - u; break; }
            running += hh[u];
        }
    }
}

// compact all anchors with bucket >= B into keys[]; key = (score_bits<<32)|~a
// -> descending key order == (score desc, idx asc) == stable top_k order.
__global__ void compact_kernel(const float* __restrict__ scores, int* sel,
                               u64* __restrict__ keys) {
    int a = blockIdx.x * blockDim.x + threadIdx.x;
    if (a >= N_ANCH) return;
    float s = scores[a];
    if (s < 0.0f) return;
    unsigned bits = __float_as_uint(s);
    if ((int)(bits >> 16) < sel[0]) return;
    int pos = atomicAdd(&sel[2], 1);
    if (pos < KCAP) keys[pos] = ((u64)bits << 32) | (unsigned)(~a);
}

// fused rank + scatter, single pass: rank[i] = #{j: key_j > key_i} computed
// fully per thread (keys unique -> ranks a permutation; 0..4095 = top-4096),
// then scatter + box decode inline. No rank buffer, no zeroing, no atomics.
__global__ void rank_scatter_kernel(const float* __restrict__ x,
                                    const u64* __restrict__ keys,
                                    const int* __restrict__ sel,
                                    int* __restrict__ sidx, float* __restrict__ sscore,
                                    float* __restrict__ boxes) {
    __shared__ u64 tile[2048];
    int n = sel[2]; if (n > KCAP) n = KCAP;
    if (blockIdx.x * 256 >= n) return;
    int i = blockIdx.x * 256 + threadIdx.x;
    u64 myKey = (i < n) ? keys[i] : 0ull;
    int cnt = 0;
    for (int t0 = 0; t0 < n; t0 += 2048) {
        int m = n - t0; if (m > 2048) m = 2048;
        __syncthreads();
        for (int j = threadIdx.x; j < m; j += 256) tile[j] = keys[t0 + j];
        __syncthreads();
        int j = 0;
        for (; j + 3 < m; j += 4) {
            cnt += (tile[j]     > myKey);
            cnt += (tile[j + 1] > myKey);
            cnt += (tile[j + 2] > myKey);
            cnt += (tile[j + 3] > myKey);
        }
        for (; j < m; ++j) cnt += (tile[j] > myKey);
    }
    if (i >= n || cnt >= TOPKN) return;
    int r = cnt;
    u64 k = myKey;
    int a = (int)(~(unsigned)(k & 0xFFFFFFFFull));
    sidx[r]   = a;
    sscore[r] = __uint_as_float((unsigned)(k >> 32));
    const float* p = x + (size_t)a * DIMV;
    float xc = p[0], yc = p[1], w = p[2], h = p[3];
    float hw = __fmul_rn(w, 0.5f);
    float hh = __fmul_rn(h, 0.5f);
    boxes[r * 4 + 0] = __fsub_rn(yc, hh);
    boxes[r * 4 + 1] = __fsub_rn(xc, hw);
    boxes[r * 4 + 2] = __fadd_rn(yc, hh);
    boxes[r * 4 + 3] = __fadd_rn(xc, hw);
}

__device__ __forceinline__ u64 readlane64(u64 v, int l) {
    unsigned lo = (unsigned)__builtin_amdgcn_readlane((int)(unsigned)(v & 0xFFFFFFFFull), l);
    unsigned hi = (unsigned)__builtin_amdgcn_readlane((int)(unsigned)(v >> 32), l);
    return ((u64)hi << 32) | lo;
}

// IoU test, op-for-op identical to the (passing) prior iou_mask kernels.
// b layout: (x=y1, y=x1, z=y2, w=x2).
__device__ __forceinline__ bool iou_gt(const float4& rv, float ra,
                                       const float4& cv, float ca) {
    float iy1 = fmaxf(rv.x, cv.x);
    float ix1 = fmaxf(rv.y, cv.y);
    float iy2 = fminf(rv.z, cv.z);
    float ix2 = fminf(rv.w, cv.w);
    float ih = fmaxf(__fsub_rn(iy2, iy1), 0.0f);
    float iw = fmaxf(__fsub_rn(ix2, ix1), 0.0f);
    float inter = __fmul_rn(ih, iw);
    float uni = __fsub_rn(__fadd_rn(ra, ca), inter);
    float iou = __fdiv_rn(inter, fmaxf(uni, 1e-9f));
    return iou > 0.45f;
}

// Fused IoU + greedy scan + output. One block, 512 threads (8 waves).
// LDS: bx 64K + ar 16K + diag 32K + remv 512B + keepList/sArr/info ~1.6K.
__global__ void __launch_bounds__(512, 1)
nms_fused_kernel(const float* __restrict__ boxesG,
                 const float* __restrict__ sscore,
                 const float* __restrict__ x,
                 const int* __restrict__ sidx,
                 const int* __restrict__ cls,
                 float* __restrict__ out) {
    __shared__ __align__(16) float4 bx[TOPKN];     // 65536 B
    __shared__ float ar[TOPKN];                    // 16384 B
    __shared__ u64 diagL[4096];                    // 32768 B
    __shared__ u64 remv[64];
    __shared__ int keepListL[64];
    __shared__ int info[4];                        // [0]=count [1]=kb [2]=K
    __shared__ int sArrL[MAXDET];

    int tid  = threadIdx.x;
    int wave = tid >> 6, lane = tid & 63;

    // ---- load boxes + areas (coalesced), init remv ------------------------
    const float4* bp = (const float4*)boxesG;
    for (int i = tid; i < TOPKN; i += 512) {
        float4 b = bp[i];
        bx[i] = b;
        ar[i] = __fmul_rn(__fsub_rn(b.z, b.x), __fsub_rn(b.w, b.y));
    }
    if (tid < 64) remv[tid] = 0ull;
    if (tid == 0) info[0] = 0;
    __syncthreads();

    // ---- diag precompute: tile t rows 64t+lane, 8 tiles per wave ----------
    for (int t = wave; t < 64; t += 8) {
        int r = (t << 6) + lane;
        float4 rv = bx[r];
        float  ra = ar[r];
        u64 bits = 0ull;
        for (int j = 0; j < 64; ++j) {             // bx[(t<<6)+j]: broadcast reads
            int cj = (t << 6) + j;
            if (iou_gt(rv, ra, bx[cj], ar[cj]) && j > lane) bits |= (1ull << j);
        }
        diagL[(t << 6) + lane] = bits;
    }
    // own 8 slots -> registers (static indexing only; rule: no runtime idx)
    float4 sb[8]; float sa[8];
#pragma unroll
    for (int k = 0; k < 8; ++k) { sb[k] = bx[tid * 8 + k]; sa[k] = ar[tid * 8 + k]; }
    int aliveB = 0xFF;
    int myW = tid >> 3;                 // remv word holding my 8 slots
    int mySh = (tid & 7) * 8;           // their bit offset within the word
    __syncthreads();

    // ---- greedy scan: decisions (wave 0) + parallel suppression ----------
    for (int w = 0; w < 64; ++w) {
        u64 cand = ~remv[w];            // broadcast read; uniform
        if (cand == 0ull) continue;     // dead batch: no barriers
        if (wave == 0) {
            u64 diagv = diagL[(w << 6) | lane];
            u64 alive = cand, keptM = 0ull;
            int cnt = info[0], kb = 0;
            while (alive && cnt < MAXDET) {
                int b = (int)__builtin_ctzll(alive);       // uniform
                u64 db = readlane64(diagv, b);
                if (lane == 0) { sArrL[cnt] = (w << 6) + b; keepListL[kb] = (w << 6) + b; }
                ++cnt; ++kb;
                keptM |= (1ull << b);
                alive &= ~(db | (1ull << b));
            }
            if (lane == 0) { info[0] = cnt; info[1] = kb; remv[w] = ~keptM; }
        }
        __syncthreads();                // decisions + remv[w] visible
        if (info[0] >= MAXDET) break;   // uniform
        // suppression: this batch's keeps vs my alive future slots (registers)
        if (aliveB && tid >= ((w + 1) << 3)) {   // 8*tid >= 64*(w+1)
            int kb = info[1];
            int newSup = 0;
            for (int k = 0; k < kb; ++k) {
                int c = keepListL[k];
                float4 rv = bx[c];      // broadcast
                float  ra = ar[c];
#pragma unroll
                for (int s = 0; s < 8; ++s) {
                    if ((aliveB >> s) & 1) {
                        if (iou_gt(rv, ra, sb[s], sa[s])) {
                            aliveB &= ~(1 << s);
                            newSup |= (1 << s);
                        }
                    }
                }
                if (!aliveB) break;
            }
            if (newSup) atomicOr(&remv[myW], (u64)(unsigned)newSup << mySh);
        }
        __syncthreads();                // remv updates complete before next batch
    }

    // ---- fillers: suppressed slots (= set bits of remv) ascending --------
    __syncthreads();
    if (tid == 0) {
        int K = info[0];
        info[2] = K;
        if (K < MAXDET) {
            int filled = K;
            for (int w2 = 0; w2 < 64 && filled < MAXDET; ++w2) {
                u64 word = remv[w2];    // kept bits are 0 (remv = ~keptM)
                while (word && filled < MAXDET) {
                    int b = (int)__builtin_ctzll(word);
                    word &= word - 1;
                    sArrL[filled++] = (w2 << 6) + b;
                }
            }
        }
    }
    __syncthreads();

    // ---- output: boxes[300*4] | classes[300] | scores[300] | masks[300*32]
    int K = info[2];
    int t32 = tid & 31;
    const float* bxf = (const float*)bx;
    for (int o = tid >> 5; o < MAXDET; o += 16) {
        int s = sArrL[o];
        int a = sidx[s];
        out[1800 + o * 32 + t32] = x[(size_t)a * DIMV + 85 + t32];
        if (t32 < 4)       out[o * 4 + t32] = bxf[s * 4 + t32];
        else if (t32 == 4) out[1200 + o] = (float)cls[a];
        else if (t32 == 5) out[1500 + o] = (o < K) ? sscore[s] : -1.0f;
    }
}

extern "C" void kernel_launch(void* const* d_in, const int* in_sizes, int n_in,
                              void* d_out, int out_size, void* d_ws, size_t ws_size,
                              hipStream_t stream) {
    const float* x = (const float*)d_in[0];
    char* ws = (char*)d_ws;
    unsigned* hist   = (unsigned*)(ws + WS_HIST);
    int*      sel    = (int*)(ws + WS_SEL);
    unsigned* done   = (unsigned*)(ws + WS_DONE);
    unsigned* slices = (unsigned*)(ws + WS_SLICES);
    float*    scores = (float*)(ws + WS_SCORES);
    int*      cls    = (int*)(ws + WS_CLS);
    u64*      keys   = (u64*)(ws + WS_KEYS);
    int*      sidx   = (int*)(ws + WS_SIDX);
    float*    sscore = (float*)(ws + WS_SSC);
    float*    boxes  = (float*)(ws + WS_BOXES);

    zero_kernel<<<(NSLICE * NBUCK + 255) / 256, 256, 0, stream>>>(slices, sel, done);
    score_kernel<<<N_ANCH / SROWS, 128, 0, stream>>>(x, scores, cls, slices);
    reduce_select_kernel<<<NBUCK / 256, 256, 0, stream>>>(slices, hist, sel, done);
    compact_kernel<<<(N_ANCH + 255) / 256, 256, 0, stream>>>(scores, sel, keys);
    rank_scatter_kernel<<<KCAP / 256, 256, 0, stream>>>(x, keys, sel, sidx, sscore, boxes);
    nms_fused_kernel<<<1, 512, 0, stream>>>(boxes, sscore, x, sidx, cls, (float*)d_out);
}

// Round 8
// 392.913 us; speedup vs baseline: 1.4057x; 1.4057x over previous
//
#include <hip/hip_runtime.h>

// ---------------------------------------------------------------------------
// YOLO NMS post-processing for MI355X — 5-launch pipeline.
//
// 8-round evidence: per-iteration time ~= harness fill (42us, fixed) + kernel
// work (~75us) + ~10us per launch boundary. Round 0 (216.6us) had 10 launches.
// Scan floor is ~40us in its proven form (rounds 0-7: every alternative scan
// regressed). So this round keeps round-0's PROVEN hot kernels verbatim and
// cuts launches 10 -> 5:
//   1 zero     : hist (64KB) + sel only (slices eliminated entirely)
//   2 score_sel: scores/cls + DIRECT device-atomic histogram (no slices, no
//                reduce; ~75k atomics over ~hundreds of hot buckets, ~2-4us),
//                then last-arriving block (device ticket + threadfence, the
//                round-6-proven pattern) runs the 256-thread select.
//   3 topk     : compact -> 48-block co-resident mini-barrier (48 blocks are
//                trivially all resident on 256 CUs; ticket + spin + fences,
//                round-5/6-proven primitives) -> rank+scatter (round-6 code).
//   4 iou_mask : round-0 verbatim (full 2MB mask[r*64+colT], lower-tri zeroed).
//   5 scan_out : round-0's scan verbatim (single wave, 2-buffer LDS DMA ring,
//                raw `s_waitcnt vmcnt(32)` handoff, grouped-8 pipelined
//                ds_reads + ballot recheck) + fused output tail (4 waves).
// All IoU-relevant fp32 math uses _rn intrinsics so hipcc's default
// -ffp-contract=fast cannot fuse mul+add into fma (must match numpy fp32).
// ---------------------------------------------------------------------------

#define AS1 __attribute__((address_space(1)))
#define AS3 __attribute__((address_space(3)))

typedef unsigned long long u64;

constexpr int N_ANCH = 100800;
constexpr int DIMV   = 117;   // 4 box + 1 obj + 80 cls + 32 mask
constexpr int TOPKN  = 4096;
constexpr int MAXDET = 300;
constexpr int KCAP   = 12288; // candidate capacity
constexpr int NBUCK  = 16384; // scores < 1.0 -> bits>>16 < 0x3F80 < 16384

// workspace layout (bytes)
constexpr size_t WS_HIST   = 0;                                   // 16384 u32
constexpr size_t WS_SEL    = WS_HIST   + 65536;                   // 64 i32
                                                                  // [0]=B [2]=n [8]=tick1 [9]=tick2
constexpr size_t WS_SCORES = WS_SEL    + 256;                     // 100800 f32
constexpr size_t WS_CLS    = WS_SCORES + (size_t)N_ANCH * 4;      // 100800 i32
constexpr size_t WS_KEYS   = WS_CLS    + (size_t)N_ANCH * 4;      // 12288 u64
constexpr size_t WS_SIDX   = WS_KEYS   + (size_t)KCAP * 8;        // 4096 i32
constexpr size_t WS_SSC    = WS_SIDX   + 4096ull * 4;             // 4096 f32
constexpr size_t WS_BOXES  = WS_SSC    + 4096ull * 4;             // 4096*4 f32
constexpr size_t WS_MASK   = WS_BOXES  + 4096ull * 16;            // 4096*64 u64 = 2MB

__global__ void zero_kernel(unsigned* __restrict__ hist, int* __restrict__ sel) {
    int i = blockIdx.x * 256 + threadIdx.x;
    if (i < NBUCK) hist[i] = 0u;
    if (i < 64)    sel[i]  = 0;
}

// 128 rows per 256-thread block, staged to LDS with coalesced float4 loads.
// 2 threads per row: even lane scans classes 0..39, odd lane 40..79, merged
// via shfl_xor. Strict > keeps the first (lowest-class) argmax like numpy.
// Histogram: direct device-scope atomicAdd to the single global hist.
// Epilogue: last-arriving block (device ticket) runs select -> sel[0] = B
// with cntAbove(B) < 4096 <= cntAbove(B) + hist[B].
constexpr int SROWS  = 128;
constexpr int SBLKS  = (N_ANCH + SROWS - 1) / SROWS;   // 788 (last block: 64 rows)
__global__ void __launch_bounds__(256)
score_select_kernel(const float* __restrict__ x, float* __restrict__ scores,
                    int* __restrict__ cls, unsigned* __restrict__ hist,
                    int* __restrict__ sel) {
    __shared__ float sx[SROWS * DIMV];           // 59904 B
    int r0 = blockIdx.x * SROWS;
    int rows = N_ANCH - r0; if (rows > SROWS) rows = SROWS;
    const float4* src = (const float4*)(x + (size_t)r0 * DIMV); // 128*117*4 % 16 == 0
    float4* dst = (float4*)sx;
    int nv4 = rows * DIMV / 4;                   // 128 rows: 3744; 64 rows: 1872
    for (int i = threadIdx.x; i < nv4; i += 256) dst[i] = src[i];
    __syncthreads();
    int row  = threadIdx.x >> 1;
    int half = threadIdx.x & 1;
    if (row < rows) {
        const float* rp = sx + row * DIMV;
        float obj = rp[4];
        const float* cp = rp + 5 + half * 40;
        float best = -1.0f;
        int   bc   = half * 40;
#pragma unroll 8
        for (int c = 0; c < 40; ++c) {
            float s = __fmul_rn(cp[c], obj);
            if (s > best) { best = s; bc = half * 40 + c; }
        }
        float so = __shfl_xor(best, 1);
        int   co = __shfl_xor(bc, 1);
        if (half == 0) {
            if (so > best) { best = so; bc = co; }   // strict >: lower class wins ties
            int a = r0 + row;
            bool valid = obj > 0.25f;
            scores[a] = valid ? best : -1.0f;
            cls[a]    = bc;
            if (valid) atomicAdd(&hist[__float_as_uint(best) >> 16], 1u);
        }
    }
    // ---- last-block handshake -> select ----------------------------------
    __threadfence();                   // release scores/cls (hist is atomic)
    __syncthreads();
    __shared__ unsigned tk;
    if (threadIdx.x == 0)
        tk = __hip_atomic_fetch_add((unsigned*)&sel[8], 1u, __ATOMIC_ACQ_REL,
                                    __HIP_MEMORY_SCOPE_AGENT);
    __syncthreads();
    if (tk != (unsigned)(SBLKS - 1)) return;
    __threadfence();                   // acquire: fresh hist reads

    __shared__ unsigned sv[256];
    __shared__ int bsh[2];
    __shared__ unsigned hb64[64];
    int t = threadIdx.x;
    int base = NBUCK - 64 * (t + 1);   // chunk t = 64 buckets, t=0 = top
    const uint4* hp = (const uint4*)(hist + base);
    unsigned own = 0;
#pragma unroll
    for (int q = 0; q < 16; ++q) { uint4 v = hp[q]; own += v.x + v.y + v.z + v.w; }
    sv[t] = own;
    __syncthreads();
    for (int off = 1; off < 256; off <<= 1) {     // inclusive scan (desc-chunk order)
        unsigned v = (t >= off) ? sv[t - off] : 0u;
        __syncthreads();
        sv[t] += v;
        __syncthreads();
    }
    unsigned incl = sv[t], before = incl - own;
    if (before < (unsigned)TOPKN && incl >= (unsigned)TOPKN) {
        bsh[0] = t; bsh[1] = (int)before;
    }
    __syncthreads();
    int ts = bsh[0];
    int cbase = NBUCK - 64 * (ts + 1);
    if (t < 64) hb64[t] = hist[cbase + t];
    __syncthreads();
    if (t == 0) {
        unsigned running = (unsigned)bsh[1];
        for (int u = 63; u >= 0; --u) {           // walk winning chunk descending
            running += hb64[u];
            if (running >= (unsigned)TOPKN) { sel[0] = cbase + u; break; }
        }
    }
}

// compact -> 48-block co-resident mini-barrier -> rank+scatter.
// key = (score_bits<<32)|~a: descending key == (score desc, idx asc) ==
// stable top_k order. rank[i] = #{j: key_j > key_i} single-pass per thread
// (keys unique -> ranks a permutation; 0..4095 = sorted top-4096).
constexpr int TKB = 48;                // 48 blocks x 256 = 12288 = KCAP
__global__ void __launch_bounds__(256)
topk_kernel(const float* __restrict__ x, const float* __restrict__ scores,
            int* __restrict__ sel, u64* __restrict__ keys,
            int* __restrict__ sidx, float* __restrict__ sscore,
            float* __restrict__ boxes) {
    // ---- phase A: compact -------------------------------------------------
    int B = sel[0];
    for (int a = blockIdx.x * 256 + threadIdx.x; a < N_ANCH; a += TKB * 256) {
        float s = scores[a];
        if (s < 0.0f) continue;
        unsigned bits = __float_as_uint(s);
        if ((int)(bits >> 16) < B) continue;
        int pos = atomicAdd(&sel[2], 1);
        if (pos < KCAP) keys[pos] = ((u64)bits << 32) | (unsigned)(~a);
    }
    // ---- mini grid barrier (48 blocks, all trivially co-resident) --------
    __threadfence();                   // release keys
    __syncthreads();
    if (threadIdx.x == 0) {
        __hip_atomic_fetch_add((unsigned*)&sel[9], 1u, __ATOMIC_ACQ_REL,
                               __HIP_MEMORY_SCOPE_AGENT);
        while (__hip_atomic_load((unsigned*)&sel[9], __ATOMIC_ACQUIRE,
                                 __HIP_MEMORY_SCOPE_AGENT) < (unsigned)TKB)
            __builtin_amdgcn_s_sleep(2);
        __threadfence();               // acquire: fresh keys/sel reads
    }
    __syncthreads();
    // ---- phase B: rank + scatter (round-6 verbatim) -----------------------
    __shared__ u64 tile[2048];
    int n = sel[2]; if (n > KCAP) n = KCAP;
    if (blockIdx.x * 256 >= n) return;
    int i = blockIdx.x * 256 + threadIdx.x;
    u64 myKey = (i < n) ? keys[i] : 0ull;
    int cnt = 0;
    for (int t0 = 0; t0 < n; t0 += 2048) {
        int m = n - t0; if (m > 2048) m = 2048;
        __syncthreads();
        for (int j = threadIdx.x; j < m; j += 256) tile[j] = keys[t0 + j];
        __syncthreads();
        int j = 0;
        for (; j + 3 < m; j += 4) {
            cnt += (tile[j]     > myKey);
            cnt += (tile[j + 1] > myKey);
            cnt += (tile[j + 2] > myKey);
            cnt += (tile[j + 3] > myKey);
        }
        for (; j < m; ++j) cnt += (tile[j] > myKey);
    }
    if (i >= n || cnt >= TOPKN) return;
    int r = cnt;
    int a = (int)(~(unsigned)(myKey & 0xFFFFFFFFull));
    sidx[r]   = a;
    sscore[r] = __uint_as_float((unsigned)(myKey >> 32));
    const float* p = x + (size_t)a * DIMV;
    float xc = p[0], yc = p[1], w = p[2], h = p[3];
    float hw = __fmul_rn(w, 0.5f);
    float hh = __fmul_rn(h, 0.5f);
    boxes[r * 4 + 0] = __fsub_rn(yc, hh);
    boxes[r * 4 + 1] = __fsub_rn(xc, hw);
    boxes[r * 4 + 2] = __fadd_rn(yc, hh);
    boxes[r * 4 + 3] = __fadd_rn(xc, hw);
}

// 64x64 tile IoU bitmask (round-0 verbatim): bit j of mask[r][colT] set iff
// iou(r, colT*64+j)>0.45 && j_global>r. Lower-triangle tiles write 0.
__global__ void iou_mask_kernel(const float* __restrict__ boxes,
                                u64* __restrict__ mask) {
    int colT = blockIdx.x, rowT = blockIdx.y;
    int t = threadIdx.x;                 // 0..63
    int r = rowT * 64 + t;
    if (colT < rowT) {                   // whole tile has j < r
        mask[(size_t)r * 64 + colT] = 0ull;
        return;
    }
    __shared__ float cb[64][5];
    int cj = colT * 64 + t;
    {
        float y1 = boxes[cj * 4 + 0], x1 = boxes[cj * 4 + 1];
        float y2 = boxes[cj * 4 + 2], x2 = boxes[cj * 4 + 3];
        cb[t][0] = y1; cb[t][1] = x1; cb[t][2] = y2; cb[t][3] = x2;
        cb[t][4] = __fmul_rn(__fsub_rn(y2, y1), __fsub_rn(x2, x1));
    }
    __syncthreads();
    float ry1 = boxes[r * 4 + 0], rx1 = boxes[r * 4 + 1];
    float ry2 = boxes[r * 4 + 2], rx2 = boxes[r * 4 + 3];
    float rarea = __fmul_rn(__fsub_rn(ry2, ry1), __fsub_rn(rx2, rx1));
    u64 bitsw = 0ull;
#pragma unroll 8
    for (int j = 0; j < 64; ++j) {
        float iy1 = fmaxf(ry1, cb[j][0]);
        float ix1 = fmaxf(rx1, cb[j][1]);
        float iy2 = fminf(ry2, cb[j][2]);
        float ix2 = fminf(rx2, cb[j][3]);
        float ih = fmaxf(__fsub_rn(iy2, iy1), 0.0f);
        float iw = fmaxf(__fsub_rn(ix2, ix1), 0.0f);
        float inter = __fmul_rn(ih, iw);
        float uni = __fsub_rn(__fadd_rn(rarea, cb[j][4]), inter);
        float iou = __fdiv_rn(inter, fmaxf(uni, 1e-9f));
        if (iou > 0.45f && (colT * 64 + j) > r) bitsw |= (1ull << j);
    }
    mask[(size_t)r * 64 + colT] = bitsw;
}

// Round-0's proven scan (single wave: 2-buffer DMA ring, vmcnt(32) handoff,
// grouped-8 pipelined ds_reads + ballot recheck) + fused output tail.
__global__ void __launch_bounds__(256, 1)
nms_scan_out_kernel(const u64* __restrict__ mask,
                    const float* __restrict__ sscore,
                    const float* __restrict__ x,
                    const int* __restrict__ sidx,
                    const int* __restrict__ cls,
                    const float* __restrict__ boxes,
                    float* __restrict__ out) {
    int tid = threadIdx.x;
    __shared__ __align__(16) u64 tile[2 * 4096];   // 2 x 32 KB
    __shared__ int sArr[MAXDET];
    __shared__ u64 remvFinal[64];
    __shared__ int KK;

    if (tid < 64) {                      // ---- wave 0: round-0 scan --------
        int lane = tid;
        u64 remv = 0ull;
        int count = 0;
        auto issueBatch = [&](int w) {
            const char* gbase = (const char*)mask + (size_t)w * 32768 + (size_t)lane * 16;
            char* lbase = (char*)tile + (size_t)(w & 1) * 32768;
#pragma unroll
            for (int i = 0; i < 32; ++i) {
                __builtin_amdgcn_global_load_lds(
                    (AS1 const unsigned*)(gbase + (size_t)i * 1024),
                    (AS3 unsigned*)(lbase + (size_t)i * 1024), 16, 0, 0);
            }
        };
        issueBatch(0);
        for (int w = 0; w < 64 && count < MAXDET; ++w) {
            if (w + 1 < 64) issueBatch(w + 1);
            u64 cand = __shfl(~remv, w);              // wave-uniform
            if (!cand) continue;                      // dead batch: no wait
            // batch w landed once outstanding <= 32 (the last 32 = batch w+1)
            asm volatile("s_waitcnt vmcnt(32)" ::: "memory");
            const u64* trow = tile + (size_t)(w & 1) * 4096;
            while (cand && count < MAXDET) {
                int bs[8];
                u64 c2 = cand;
                int g = 0;
#pragma unroll
                for (int t = 0; t < 8; ++t) {
                    bs[t] = c2 ? (int)__builtin_ctzll(c2) : 0;
                    if (c2) { c2 &= c2 - 1; g = t + 1; }
                }
                u64 mvs[8];
#pragma unroll
                for (int t = 0; t < 8; ++t) {         // independent, pipelined ds_reads
                    mvs[t] = trow[(size_t)bs[t] * 64 + lane];
                }
#pragma unroll
                for (int t = 0; t < 8; ++t) {
                    if (t < g && count < MAXDET) {
                        int b = bs[t];
                        u64 bal = __ballot(((remv >> b) & 1ull) != 0);
                        if (!((bal >> w) & 1ull)) {   // still alive -> keep
                            if (lane == 0) sArr[count] = (w << 6) + b;
                            count++;
                            remv |= mvs[t];
                        }
                    }
                }
                cand = c2;
            }
        }
        remvFinal[lane] = remv;
        if (lane == 0) KK = count;
    }
    __syncthreads();                     // drains wave-0 DMA + publishes LDS
    if (tid == 0 && KK < MAXDET) {       // fillers: suppressed slots ascending
        int filled = KK;
        for (int w = 0; w < 64 && filled < MAXDET; ++w) {
            u64 word = remvFinal[w];
            while (word && filled < MAXDET) {
                int b = (int)__builtin_ctzll(word);
                word &= word - 1;
                sArr[filled++] = (w << 6) + b;
            }
        }
    }
    __syncthreads();

    // ---- output: boxes[300*4] | classes[300] | scores[300] | masks[300*32]
    int K = KK;
    int t32 = tid & 31;
    for (int o = tid >> 5; o < MAXDET; o += 8) {
        int s = sArr[o];
        int a = sidx[s];
        out[1800 + o * 32 + t32] = x[(size_t)a * DIMV + 85 + t32];
        if (t32 < 4)       out[o * 4 + t32] = boxes[s * 4 + t32];
        else if (t32 == 4) out[1200 + o] = (float)cls[a];
        else if (t32 == 5) out[1500 + o] = (o < K) ? sscore[s] : -1.0f;
    }
}

extern "C" void kernel_launch(void* const* d_in, const int* in_sizes, int n_in,
                              void* d_out, int out_size, void* d_ws, size_t ws_size,
                              hipStream_t stream) {
    const float* x = (const float*)d_in[0];
    char* ws = (char*)d_ws;
    unsigned* hist   = (unsigned*)(ws + WS_HIST);
    int*      sel    = (int*)(ws + WS_SEL);
    float*    scores = (float*)(ws + WS_SCORES);
    int*      cls    = (int*)(ws + WS_CLS);
    u64*      keys   = (u64*)(ws + WS_KEYS);
    int*      sidx   = (int*)(ws + WS_SIDX);
    float*    sscore = (float*)(ws + WS_SSC);
    float*    boxes  = (float*)(ws + WS_BOXES);
    u64*      mask   = (u64*)(ws + WS_MASK);

    zero_kernel<<<64, 256, 0, stream>>>(hist, sel);
    score_select_kernel<<<SBLKS, 256, 0, stream>>>(x, scores, cls, hist, sel);
    topk_kernel<<<TKB, 256, 0, stream>>>(x, scores, sel, keys, sidx, sscore, boxes);
    dim3 mg(64, 64);
    iou_mask_kernel<<<mg, 64, 0, stream>>>(boxes, mask);
    nms_scan_out_kernel<<<1, 256, 0, stream>>>(mask, sscore, x, sidx, cls, boxes,
                                               (float*)d_out);
}